// Round 2
// baseline (104.722 us; speedup 1.0000x reference)
//
#include <hip/hip_runtime.h>

#define B 384
#define D 512
#define R 4
#define MAIN_BLOCKS (B / R)  // 96
#define FLT_BIG 3.402823466e+38f

// ---------------- kernel 1: transpose V -> VT, plus num_pos ----------------
__global__ __launch_bounds__(256) void prep_kernel(const float* __restrict__ V,
                                                   const int* __restrict__ labels,
                                                   float* __restrict__ VT,
                                                   float* __restrict__ npos_out) {
  int bx = blockIdx.x;
  int tid = threadIdx.x;
  if (bx < 192) {
    // 32x32 tile transpose: V[384][512] -> VT[512][384]
    __shared__ float tile[32][33];
    int rt = bx % 12, ct = bx / 12;       // 12 row-tiles, 16 col-tiles
    int r0 = rt * 32, c0 = ct * 32;
    int tx = tid & 31, ty = tid >> 5;     // 32 x 8
#pragma unroll
    for (int i = ty; i < 32; i += 8)
      tile[i][tx] = V[(r0 + i) * D + (c0 + tx)];
    __syncthreads();
#pragma unroll
    for (int i = ty; i < 32; i += 8)
      VT[(c0 + i) * B + (r0 + tx)] = tile[tx][i];
  } else {
    // num_pos = (#ordered same-label pairs) - B   (depends on labels only)
    __shared__ int slab[B];
    __shared__ int redw[4];
    for (int i = tid; i < B; i += 256) slab[i] = labels[i];
    __syncthreads();
    int cnt = 0;
    for (int b = tid; b < B; b += 256) {
      int lb = slab[b];
      for (int k = 0; k < B; ++k) cnt += (slab[k] == lb) ? 1 : 0;
    }
    for (int off = 32; off > 0; off >>= 1) cnt += __shfl_down(cnt, off);
    int lane = tid & 63, wid = tid >> 6;
    if (lane == 0) redw[wid] = cnt;
    __syncthreads();
    if (tid == 0) {
      int tot = redw[0] + redw[1] + redw[2] + redw[3];
      npos_out[0] = (float)(tot - B);
    }
  }
}

// ---------------- kernel 2: fused distances + semihard loss ----------------
// One block per R=4 rows. 384 threads; thread tid plays the role of column k
// (for distance/scan work) and of candidate positive b (for list building).
__global__ __launch_bounds__(B) void semihard_kernel(const float* __restrict__ V,
                                                     const float* __restrict__ VT,
                                                     const int* __restrict__ labels,
                                                     const float* __restrict__ npos_p,
                                                     float* __restrict__ out) {
  __shared__ __align__(16) float va4[D][R];  // va4[j][r] = V[a0+r][j]
  __shared__ float dmat[R][B];
  __shared__ float sq_sh[B];
  __shared__ int slab[B];
  __shared__ float redf[8];
  __shared__ int plist[64];
  __shared__ int pcnt;

  const int tid = threadIdx.x;
  const int a0 = blockIdx.x * R;
  const int lane = tid & 63, wid = tid >> 6;

  slab[tid] = labels[tid];
  for (int idx = tid; idx < D * R; idx += B) {
    int j = idx >> 2, r = idx & 3;
    va4[j][r] = V[(a0 + r) * D + j];
  }
  __syncthreads();

  // ---- phase 1: dots. thread = column k; coalesced reads of VT rows ----
  float acc0 = 0.f, acc1 = 0.f, acc2 = 0.f, acc3 = 0.f, sqk = 0.f;
  const float* vtk = VT + tid;
#pragma unroll 8
  for (int j = 0; j < D; ++j) {
    float vkj = vtk[j * B];
    float4 va = *(const float4*)(&va4[j][0]);  // LDS broadcast
    acc0 = fmaf(vkj, va.x, acc0);
    acc1 = fmaf(vkj, va.y, acc1);
    acc2 = fmaf(vkj, va.z, acc2);
    acc3 = fmaf(vkj, va.w, acc3);
    sqk = fmaf(vkj, vkj, sqk);
  }
  sq_sh[tid] = sqk;
  __syncthreads();

  // ---- distances for the 4 owned rows ----
  {
    float accs[R] = {acc0, acc1, acc2, acc3};
#pragma unroll
    for (int r = 0; r < R; ++r) {
      float d2 = sq_sh[a0 + r] + sqk - 2.0f * accs[r];
      d2 = fmaxf(d2, 0.0f);
      float dd = (d2 <= 0.0f) ? 0.0f : sqrtf(d2);
      if (tid == a0 + r) dd = 0.0f;  // zero diagonal
      dmat[r][tid] = dd;
    }
  }
  __syncthreads();

  const float npos = npos_p[0];
  const int lb = slab[tid];
  float rsum = 0.0f;  // accumulated by thread 0 only

#pragma unroll 1
  for (int r = 0; r < R; ++r) {
    const int la = slab[a0 + r];
    const bool negk = (lb != la);
    const float dk = dmat[r][tid];

    // neg_in = max(0, max over negatives of d[a,k])  (row_min == 0 exactly)
    float v = negk ? dk : 0.0f;
    for (int off = 32; off > 0; off >>= 1) v = fmaxf(v, __shfl_down(v, off));
    if (lane == 0) redf[wid] = v;
    if (tid == 0) pcnt = 0;
    __syncthreads();

    float neg_in = 0.0f;
    if (tid == 0) {
      neg_in = redf[0];
#pragma unroll
      for (int w = 1; w < 6; ++w) neg_in = fmaxf(neg_in, redf[w]);
    }
    // gather this row's positive columns
    if ((lb == la) && (tid != a0 + r)) {
      int p = atomicAdd(&pcnt, 1);
      if (p < 64) plist[p] = tid;
    }
    __syncthreads();

    int np = pcnt;
    if (np > 64) np = 64;
    for (int p = 0; p < np; ++p) {
      const int b = plist[p];
      const float db = dmat[r][b];  // broadcast
      float cand = (negk && dk > db) ? dk : FLT_BIG;
      for (int off = 32; off > 0; off >>= 1) cand = fminf(cand, __shfl_down(cand, off));
      if (lane == 0) redf[wid] = cand;
      __syncthreads();
      if (tid == 0) {
        float m = redf[0];
#pragma unroll
        for (int w = 1; w < 6; ++w) m = fminf(m, redf[w]);
        float semi = (m < 3.0e38f) ? m : neg_in;  // exists -> neg_out else neg_in
        rsum += fmaxf(db - semi + 1.0f, 0.0f);    // MARGIN = 1
      }
      __syncthreads();
    }
  }

  if (tid == 0) atomicAdd(out, rsum / npos);
}

extern "C" void kernel_launch(void* const* d_in, const int* in_sizes, int n_in,
                              void* d_out, int out_size, void* d_ws, size_t ws_size,
                              hipStream_t stream) {
  const float* V = (const float*)d_in[0];
  const int* labels = (const int*)d_in[1];
  float* outp = (float*)d_out;
  float* VT = (float*)d_ws;                 // 512*384 floats = 786432 B
  float* npos_slot = VT + (size_t)D * B;    // 1 float
  hipMemsetAsync(d_out, 0, sizeof(float), stream);
  prep_kernel<<<dim3(193), 256, 0, stream>>>(V, labels, VT, npos_slot);
  semihard_kernel<<<dim3(MAIN_BLOCKS), B, 0, stream>>>(V, VT, labels, npos_slot, outp);
}

// Round 3
// 75.896 us; speedup vs baseline: 1.3798x; 1.3798x over previous
//
#include <hip/hip_runtime.h>

#define NB 384          // batch
#define ND 512          // dim
#define FLT_BIG 3.0e38f

// ws layout (floats): G[384*384] @ 0 ; sq[384] @ 147456 ; npos @ 147840
// total < 600 KB (previous kernel proved 786 KB of ws works)

// ---------------- prep: sq[row] + num_pos via label histogram ----------------
__global__ __launch_bounds__(64) void prep_kernel(const float* __restrict__ V,
                                                  const int* __restrict__ labels,
                                                  float* __restrict__ sq,
                                                  float* __restrict__ npos) {
  const int bx = blockIdx.x;
  const int lane = threadIdx.x;
  if (bx < NB) {
    const float4* row = (const float4*)(V + (size_t)bx * ND);
    float4 v0 = row[lane * 2];
    float4 v1 = row[lane * 2 + 1];
    float acc = v0.x * v0.x + v0.y * v0.y + v0.z * v0.z + v0.w * v0.w +
                v1.x * v1.x + v1.y * v1.y + v1.z * v1.z + v1.w * v1.w;
#pragma unroll
    for (int off = 32; off; off >>= 1) acc += __shfl_xor(acc, off);
    if (lane == 0) sq[bx] = acc;
  } else {
    // num_pos = sum_c count[c]^2 - NB   (labels in [0,64))
    __shared__ int cnt[64];
    cnt[lane] = 0;
    __syncthreads();
#pragma unroll
    for (int i = 0; i < 6; ++i) atomicAdd(&cnt[labels[lane + 64 * i]], 1);
    __syncthreads();
    int c = cnt[lane];
    int s = c * c;
#pragma unroll
    for (int off = 32; off; off >>= 1) s += __shfl_xor(s, off);
    if (lane == 0) npos[0] = (float)(s - NB);
  }
}

// ---------------- gram: G += V[a-tile] . V[b-tile]^T over one k-slice ----------------
// grid (6,6,8): x=b-tile, y=a-tile, z=k-slice of 64. 64x64 tile, 4x4 per thread.
__global__ __launch_bounds__(256) void gram_kernel(const float* __restrict__ V,
                                                   float* __restrict__ G) {
  __shared__ float As[64][68];  // pad 68: a-reads 4 distinct banks, b-reads 2-way (free)
  __shared__ float Bs[64][68];
  const int tid = threadIdx.x;
  const int a0 = blockIdx.y * 64, b0 = blockIdx.x * 64, k0 = blockIdx.z * 64;

  // stage both 64x64 tiles, fully coalesced float4
#pragma unroll
  for (int it = 0; it < 4; ++it) {
    int f = tid + it * 256;            // float4 id 0..1023
    int row = f >> 4, c4 = (f & 15) << 2;
    *(float4*)&As[row][c4] = *(const float4*)&V[(size_t)(a0 + row) * ND + k0 + c4];
    *(float4*)&Bs[row][c4] = *(const float4*)&V[(size_t)(b0 + row) * ND + k0 + c4];
  }
  __syncthreads();

  const int tx = tid & 15, ty = tid >> 4;
  float acc[4][4] = {};
#pragma unroll
  for (int kk = 0; kk < 64; kk += 4) {
    float4 av[4], bv[4];
#pragma unroll
    for (int i = 0; i < 4; ++i) {
      av[i] = *(const float4*)&As[ty + 16 * i][kk];
      bv[i] = *(const float4*)&Bs[tx + 16 * i][kk];
    }
#pragma unroll
    for (int i = 0; i < 4; ++i)
#pragma unroll
      for (int j = 0; j < 4; ++j) {
        acc[i][j] = fmaf(av[i].x, bv[j].x, acc[i][j]);
        acc[i][j] = fmaf(av[i].y, bv[j].y, acc[i][j]);
        acc[i][j] = fmaf(av[i].z, bv[j].z, acc[i][j]);
        acc[i][j] = fmaf(av[i].w, bv[j].w, acc[i][j]);
      }
  }
#pragma unroll
  for (int i = 0; i < 4; ++i)
#pragma unroll
    for (int j = 0; j < 4; ++j)
      atomicAdd(&G[(size_t)(a0 + ty + 16 * i) * NB + (b0 + tx + 16 * j)], acc[i][j]);
}

// ---------------- loss: one wave per row a, no barriers ----------------
__global__ __launch_bounds__(64) void loss_kernel(const float* __restrict__ G,
                                                  const float* __restrict__ sq,
                                                  const int* __restrict__ labels,
                                                  const float* __restrict__ npos,
                                                  float* __restrict__ out) {
  const int a = blockIdx.x;
  const int lane = threadIdx.x;
  const float sqa = sq[a];
  const int la = labels[a];

  float dk[6];
  int same[6];
  float neg_in = 0.0f;
#pragma unroll
  for (int i = 0; i < 6; ++i) {
    const int k = lane + (i << 6);
    const float g = G[(size_t)a * NB + k];
    float d2 = sqa + sq[k] - 2.0f * g;
    d2 = fmaxf(d2, 0.0f);
    float d = (d2 <= 0.0f) ? 0.0f : sqrtf(d2);
    if (k == a) d = 0.0f;               // zero diagonal (matches reference)
    dk[i] = d;
    same[i] = (labels[k] == la);
    if (!same[i]) neg_in = fmaxf(neg_in, d);   // row_min == 0 exactly
  }
#pragma unroll
  for (int off = 32; off; off >>= 1) neg_in = fmaxf(neg_in, __shfl_xor(neg_in, off));

  float rsum = 0.0f;
#pragma unroll 1
  for (int i = 0; i < 6; ++i) {
    const int k = lane + (i << 6);
    unsigned long long pm = __ballot(same[i] && (k != a));   // positives in this slice
    while (pm) {
      const int src = __builtin_ctzll(pm);
      pm &= pm - 1;
      const float db = __shfl(dk[i], src);   // d[a, b] broadcast
      // min over negatives k with d[a,k] > db
      float m = FLT_BIG;
#pragma unroll
      for (int t = 0; t < 6; ++t) {
        const float c = (!same[t] && dk[t] > db) ? dk[t] : FLT_BIG;
        m = fminf(m, c);
      }
#pragma unroll
      for (int off = 32; off; off >>= 1) m = fminf(m, __shfl_xor(m, off));
      const float semi = (m < 1.0e38f) ? m : neg_in;  // exists -> neg_out else neg_in
      rsum += fmaxf(db - semi + 1.0f, 0.0f);          // MARGIN = 1
    }
  }
  if (lane == 0) atomicAdd(out, rsum / npos[0]);
}

extern "C" void kernel_launch(void* const* d_in, const int* in_sizes, int n_in,
                              void* d_out, int out_size, void* d_ws, size_t ws_size,
                              hipStream_t stream) {
  const float* V = (const float*)d_in[0];
  const int* labels = (const int*)d_in[1];
  float* outp = (float*)d_out;
  float* G = (float*)d_ws;
  float* sq = G + (size_t)NB * NB;      // 147456
  float* npos = sq + NB;                // 147840
  hipMemsetAsync(G, 0, (size_t)NB * NB * sizeof(float), stream);
  hipMemsetAsync(d_out, 0, sizeof(float), stream);
  prep_kernel<<<dim3(NB + 1), 64, 0, stream>>>(V, labels, sq, npos);
  gram_kernel<<<dim3(6, 6, 8), 256, 0, stream>>>(V, G);
  loss_kernel<<<dim3(NB), 64, 0, stream>>>(G, sq, labels, npos, outp);
}

// Round 4
// 69.470 us; speedup vs baseline: 1.5074x; 1.0925x over previous
//
#include <hip/hip_runtime.h>

#define NB 384          // batch
#define ND 512          // dim
#define KS 8            // k-slices
#define FLT_BIG 3.0e38f

// ws layout (floats): Gp[8][384][384] @ 0 ; sq[384] ; npos[1]   (< 5 MB of 256 MB ws)

// ---------- kernel A: split-K gram partials (no atomics) + sq + npos + out=0 ----------
// grid 175: blocks 0..167 = 8 k-slices x 21 upper tiles (mirror-stored);
//           blocks 168..173 = sq (64 rows each); block 174 = npos + zero out.
__global__ __launch_bounds__(256) void gram_prep_kernel(const float* __restrict__ V,
                                                        const int* __restrict__ labels,
                                                        float* __restrict__ Gp,
                                                        float* __restrict__ sq,
                                                        float* __restrict__ npos,
                                                        float* __restrict__ out0) {
  const int bx = blockIdx.x;
  const int tid = threadIdx.x;
  if (bx < 168) {
    __shared__ float As[64][68];
    __shared__ float Bs[64][68];
    const int ks = bx / 21;
    int rem = bx % 21;
    int ti = 0, cnt = 6;
    while (rem >= cnt) { rem -= cnt; --cnt; ++ti; }   // triangular tile pair
    const int tj = ti + rem;
    const int a0 = ti * 64, b0 = tj * 64, k0 = ks * 64;

#pragma unroll
    for (int it = 0; it < 4; ++it) {
      int f = tid + it * 256;            // float4 id 0..1023
      int row = f >> 4, c4 = (f & 15) << 2;
      *(float4*)&As[row][c4] = *(const float4*)&V[(size_t)(a0 + row) * ND + k0 + c4];
      *(float4*)&Bs[row][c4] = *(const float4*)&V[(size_t)(b0 + row) * ND + k0 + c4];
    }
    __syncthreads();

    const int tx = tid & 15, ty = tid >> 4;
    float acc[4][4] = {};
#pragma unroll
    for (int kk = 0; kk < 64; kk += 4) {
      float4 av[4], bv[4];
#pragma unroll
      for (int i = 0; i < 4; ++i) {
        av[i] = *(const float4*)&As[ty + 16 * i][kk];
        bv[i] = *(const float4*)&Bs[tx + 16 * i][kk];
      }
#pragma unroll
      for (int i = 0; i < 4; ++i)
#pragma unroll
        for (int j = 0; j < 4; ++j) {
          acc[i][j] = fmaf(av[i].x, bv[j].x, acc[i][j]);
          acc[i][j] = fmaf(av[i].y, bv[j].y, acc[i][j]);
          acc[i][j] = fmaf(av[i].z, bv[j].z, acc[i][j]);
          acc[i][j] = fmaf(av[i].w, bv[j].w, acc[i][j]);
        }
    }
    float* Gk = Gp + (size_t)ks * NB * NB;
#pragma unroll
    for (int i = 0; i < 4; ++i)
#pragma unroll
      for (int j = 0; j < 4; ++j) {
        const int ar = a0 + ty + 16 * i, bc = b0 + tx + 16 * j;
        Gk[(size_t)ar * NB + bc] = acc[i][j];
        Gk[(size_t)bc * NB + ar] = acc[i][j];   // symmetric mirror (same value on diag tiles)
      }
  } else if (bx < 174) {
    // sq for 64 rows: thread = (row quarter), 4 lanes per row
    const int r = (bx - 168) * 64 + (tid >> 2);
    const int q = tid & 3;
    const float4* p = (const float4*)(V + (size_t)r * ND + q * 128);
    float s = 0.f;
#pragma unroll 8
    for (int i = 0; i < 32; ++i) {
      float4 v = p[i];
      s += v.x * v.x + v.y * v.y + v.z * v.z + v.w * v.w;
    }
    s += __shfl_xor(s, 1);
    s += __shfl_xor(s, 2);
    if (q == 0) sq[r] = s;
  } else {
    // num_pos = sum_c count[c]^2 - NB ; zero the output slot
    __shared__ int cnt[64];
    if (tid < 64) cnt[tid] = 0;
    __syncthreads();
    for (int i = tid; i < NB; i += 256) atomicAdd(&cnt[labels[i]], 1);
    __syncthreads();
    if (tid < 64) {
      int c = cnt[tid];
      int s = c * c;
#pragma unroll
      for (int off = 32; off; off >>= 1) s += __shfl_xor(s, off);
      if (tid == 0) {
        npos[0] = (float)(s - NB);
        out0[0] = 0.0f;
      }
    }
  }
}

// ---------- kernel B: one wave per row a, no barriers ----------
__global__ __launch_bounds__(64) void loss_kernel(const float* __restrict__ Gp,
                                                  const float* __restrict__ sq,
                                                  const int* __restrict__ labels,
                                                  const float* __restrict__ npos,
                                                  float* __restrict__ out) {
  const int a = blockIdx.x;
  const int lane = threadIdx.x;
  const float sqa = sq[a];
  const int la = labels[a];

  float dk[6];
  int same[6];
  float neg_in = 0.0f;
#pragma unroll
  for (int i = 0; i < 6; ++i) {
    const int k = lane + (i << 6);
    float g = 0.f;
#pragma unroll
    for (int p = 0; p < KS; ++p) g += Gp[(size_t)p * NB * NB + (size_t)a * NB + k];
    float d2 = sqa + sq[k] - 2.0f * g;
    d2 = fmaxf(d2, 0.0f);
    float d = (d2 <= 0.0f) ? 0.0f : sqrtf(d2);
    if (k == a) d = 0.0f;               // zero diagonal (matches reference)
    dk[i] = d;
    same[i] = (labels[k] == la);
    if (!same[i]) neg_in = fmaxf(neg_in, d);   // row_min == 0 exactly
  }
#pragma unroll
  for (int off = 32; off; off >>= 1) neg_in = fmaxf(neg_in, __shfl_xor(neg_in, off));

  float rsum = 0.0f;
#pragma unroll 1
  for (int i = 0; i < 6; ++i) {
    const int k = lane + (i << 6);
    unsigned long long pm = __ballot(same[i] && (k != a));   // positives in this slice
    while (pm) {
      const int src = __builtin_ctzll(pm);
      pm &= pm - 1;
      const float db = __shfl(dk[i], src);   // d[a,b] broadcast
      float m = FLT_BIG;                     // min over negs with d[a,k] > db
#pragma unroll
      for (int t = 0; t < 6; ++t) {
        const float c = (!same[t] && dk[t] > db) ? dk[t] : FLT_BIG;
        m = fminf(m, c);
      }
#pragma unroll
      for (int off = 32; off; off >>= 1) m = fminf(m, __shfl_xor(m, off));
      const float semi = (m < 1.0e38f) ? m : neg_in;  // exists -> neg_out else neg_in
      rsum += fmaxf(db - semi + 1.0f, 0.0f);          // MARGIN = 1
    }
  }
  if (lane == 0) atomicAdd(out, rsum / npos[0]);
}

extern "C" void kernel_launch(void* const* d_in, const int* in_sizes, int n_in,
                              void* d_out, int out_size, void* d_ws, size_t ws_size,
                              hipStream_t stream) {
  const float* V = (const float*)d_in[0];
  const int* labels = (const int*)d_in[1];
  float* outp = (float*)d_out;
  float* Gp = (float*)d_ws;                         // 8*384*384 floats
  float* sq = Gp + (size_t)KS * NB * NB;
  float* npos = sq + NB;
  gram_prep_kernel<<<dim3(175), 256, 0, stream>>>(V, labels, Gp, sq, npos, outp);
  loss_kernel<<<dim3(NB), 64, 0, stream>>>(Gp, sq, labels, npos, outp);
}